// Round 12
// baseline (283.196 us; speedup 1.0000x reference)
//
#include <hip/hip_runtime.h>

#define E_N     100000
#define USER_N  100000
#define NROW    200000
#define NB_ACC  256
#define BIN_CAP 16384
#define E_PAD   114688  // 256 blocks * 7 chunks * 64 edges
#define ACC_NCH 7
#define ACC_CHUNK 64
#define BUCKET_CAP 16
#define NB_INIT 782     // 782*256 = 200192 >= NROW+2
#define NB_CONV 1792    // E_PAD/64

typedef __bf16 bf16x8 __attribute__((ext_vector_type(8)));
typedef __bf16 bf16x4 __attribute__((ext_vector_type(4)));
typedef float  f32x4  __attribute__((ext_vector_type(4)));

__device__ __forceinline__ float leaky(float x) { return x > 0.f ? x : 0.5f * x; }

// -------- prep: init counts + Tt build + hyper conversion (batched loads, swizzled LDS) --------
// blocks [0, NB_INIT): zero cnt/cnt8; first 8 also build Tt[v][k][d] = T[v][d][k] bf16
// blocks [NB_INIT, ..): hyper fp32 [E,128] -> hyperT bf16 [128][E_PAD] + hyperB bf16 [E][128].
// All 8 tile loads issued before any conversion (MLP=8 per thread, was 1).
__global__ void __launch_bounds__(256) prepKernel(
    int* __restrict__ cnt, int* __restrict__ cnt8,
    const float* __restrict__ T, __bf16* __restrict__ Tt,
    const float* __restrict__ hyper, __bf16* __restrict__ hyperT,
    __bf16* __restrict__ hyperB) {
  __shared__ __bf16 sT[128][72];
  const int b = blockIdx.x;
  const int tid = threadIdx.x;
  if (b < NB_INIT) {
    const int i = b * 256 + tid;
    if (i < NROW + 2) cnt[i] = 0;
    if (i < 8) cnt8[i] = 0;
    if (b < 8) {
      const float* Tv = T + (size_t)b * 4096;
      __bf16* Tb = Tt + (size_t)b * 4096;
      for (int idx = tid; idx < 4096; idx += 256) {
        const int d = idx >> 6, k = idx & 63;
        Tb[k * 64 + d] = (__bf16)Tv[idx];
      }
    }
    return;
  }
  const int cb = b - NB_INIT;
  const int e0 = cb * 64;
  const int h = tid >> 1, eoff = (tid & 1) * 32;
  if (e0 >= E_N) {
    const float4 z = make_float4(0.f, 0.f, 0.f, 0.f);
    #pragma unroll
    for (int q = 0; q < 4; ++q)
      *(float4*)((char*)(hyperT + (size_t)h * E_PAD + e0 + eoff) + q * 16) = z;
    return;
  }
  // batch all 8 loads first
  float4 v[8];
  #pragma unroll
  for (int r = 0; r < 8; ++r) {
    const int idx = r * 256 + tid;
    const int e = idx >> 5, h4 = (idx & 31) * 4;
    v[r] = make_float4(0.f, 0.f, 0.f, 0.f);
    if (e0 + e < E_N) v[r] = *(const float4*)(hyper + (size_t)(e0 + e) * 128 + h4);
  }
  // convert + store (hyperB global, sT swizzled LDS)
  #pragma unroll
  for (int r = 0; r < 8; ++r) {
    const int idx = r * 256 + tid;
    const int e = idx >> 5, h4 = (idx & 31) * 4;
    const int ce = e ^ ((idx & 15) * 4);
    bf16x4 pk;
    pk[0] = (__bf16)v[r].x; pk[1] = (__bf16)v[r].y;
    pk[2] = (__bf16)v[r].z; pk[3] = (__bf16)v[r].w;
    if (e0 + e < E_N)
      *(bf16x4*)(hyperB + (size_t)(e0 + e) * 128 + h4) = pk;
    sT[h4 + 0][ce] = pk[0]; sT[h4 + 1][ce] = pk[1];
    sT[h4 + 2][ce] = pk[2]; sT[h4 + 3][ce] = pk[3];
  }
  __syncthreads();
  const int swz = ((h >> 2) & 15) * 4;
  #pragma unroll
  for (int q = 0; q < 8; ++q) {
    const bf16x4 vv = *(const bf16x4*)&sT[h][(eoff + q * 4) ^ swz];
    *(bf16x4*)(hyperT + (size_t)h * E_PAD + e0 + eoff + q * 4) = vv;
  }
}

// -------- binning by etype + direct bucket fill --------
__global__ void binKernel(const int* __restrict__ val, const int* __restrict__ src,
                          const int* __restrict__ tgt,
                          int* __restrict__ perm, int* __restrict__ permSrc,
                          int* __restrict__ permTgt,
                          int* __restrict__ cnt8, int* __restrict__ cnt,
                          int* __restrict__ list) {
  __shared__ int lh[8], lbase[8];
  const int tid = threadIdx.x;
  if (tid < 8) lh[tid] = 0;
  __syncthreads();
  const int e = blockIdx.x * 256 + tid;
  int v = -1, slot = 0, s = 0, t = 0;
  if (e < E_N) {
    v = val[e]; s = src[e]; t = tgt[e];
    slot = atomicAdd(&lh[v], 1);
    const int ps = atomicAdd(&cnt[s], 1);
    if (ps < BUCKET_CAP) list[(size_t)s * BUCKET_CAP + ps] = e;
    const int pt = atomicAdd(&cnt[USER_N + t], 1);
    if (pt < BUCKET_CAP) list[(size_t)(USER_N + t) * BUCKET_CAP + pt] = e;
  }
  __syncthreads();
  if (tid < 8) lbase[tid] = atomicAdd(&cnt8[tid], lh[tid]);
  __syncthreads();
  if (v >= 0) {
    const int p = v * BIN_CAP + lbase[v] + slot;
    perm[p] = e; permSrc[p] = s; permTgt[p] = t;
  }
}

// -------- Stage A: 32 edges/wave (2 subtiles), batched gathers, 1024 blocks for TLP --------
__global__ void __launch_bounds__(256) stageAMfmaKernel(
    const float* __restrict__ uE, const float* __restrict__ iE, const __bf16* __restrict__ Tt,
    const int* __restrict__ permSrc, const int* __restrict__ permTgt,
    const int* __restrict__ perm, const int* __restrict__ cnt8,
    float* __restrict__ edge) {
  __shared__ float sC[4][16][68];
  const int v  = blockIdx.y;
  const int nE = min(cnt8[v], BIN_CAP);
  const int tid  = threadIdx.x;
  const int lane = tid & 63;
  const int wave = tid >> 6;
  const int l16 = lane & 15, quad = lane >> 4;
  const int wbase = blockIdx.x * 128 + wave * 32;   // this wave's 32 edges
  if (wbase >= nE) return;

  bf16x8 Bf[2][4];
  #pragma unroll
  for (int kc = 0; kc < 2; ++kc)
    #pragma unroll
    for (int nt = 0; nt < 4; ++nt)
      Bf[kc][nt] = *(const bf16x8*)(Tt + (size_t)v * 4096 + (nt * 16 + l16) * 64 + kc * 32 + quad * 8);

  int sI[2], tI[2], eI[2];
  #pragma unroll
  for (int s = 0; s < 2; ++s) {
    const int eoffS = wbase + s * 16;
    const bool lv = (eoffS + l16 < nE);
    const int p = v * BIN_CAP + (lv ? eoffS + l16 : 0);
    sI[s] = permSrc[p]; tI[s] = permTgt[p]; eI[s] = perm[p];
  }

  float4 f0[2][2], f1[2][2];
  #pragma unroll
  for (int s = 0; s < 2; ++s)
    #pragma unroll
    for (int kc = 0; kc < 2; ++kc) {
      const float* ap = uE + (size_t)sI[s] * 64 + kc * 32 + quad * 8;
      f0[s][kc] = *(const float4*)ap;
      f1[s][kc] = *(const float4*)(ap + 4);
    }

  const int r  = lane >> 2;
  const int c0 = (lane & 3) * 4;

  // iE prefetch for both subtiles
  float4 iv[2][4];
  int tj2[2], gj2[2];
  #pragma unroll
  for (int sh = 0; sh < 2; ++sh) {
    tj2[sh] = __shfl(tI[sh], r, 64);
    gj2[sh] = __shfl(eI[sh], r, 64);
    #pragma unroll
    for (int q = 0; q < 4; ++q)
      iv[sh][q] = *(const float4*)(iE + (size_t)tj2[sh] * 64 + c0 + q * 16);
  }

  f32x4 acc[2][4];
  #pragma unroll
  for (int sh = 0; sh < 2; ++sh)
    #pragma unroll
    for (int nt = 0; nt < 4; ++nt) acc[sh][nt] = (f32x4){0.f, 0.f, 0.f, 0.f};
  #pragma unroll
  for (int sh = 0; sh < 2; ++sh) {
    #pragma unroll
    for (int kc = 0; kc < 2; ++kc) {
      bf16x8 a;
      a[0] = (__bf16)f0[sh][kc].x; a[1] = (__bf16)f0[sh][kc].y;
      a[2] = (__bf16)f0[sh][kc].z; a[3] = (__bf16)f0[sh][kc].w;
      a[4] = (__bf16)f1[sh][kc].x; a[5] = (__bf16)f1[sh][kc].y;
      a[6] = (__bf16)f1[sh][kc].z; a[7] = (__bf16)f1[sh][kc].w;
      #pragma unroll
      for (int nt = 0; nt < 4; ++nt)
        acc[sh][nt] = __builtin_amdgcn_mfma_f32_16x16x32_bf16(a, Bf[kc][nt], acc[sh][nt], 0, 0, 0);
    }
  }
  #pragma unroll
  for (int sh = 0; sh < 2; ++sh) {
    const int eoffS = wbase + sh * 16;
    #pragma unroll
    for (int nt = 0; nt < 4; ++nt)
      #pragma unroll
      for (int reg = 0; reg < 4; ++reg)
        sC[wave][quad * 4 + reg][nt * 16 + l16] = acc[sh][nt][reg];
    if (eoffS + r < nE) {
      #pragma unroll
      for (int q = 0; q < 4; ++q) {
        const int c = c0 + q * 16;
        const float4 cv = *(const float4*)&sC[wave][r][c];
        float4 rr;
        rr.x = cv.x * iv[sh][q].x; rr.y = cv.y * iv[sh][q].y;
        rr.z = cv.z * iv[sh][q].z; rr.w = cv.w * iv[sh][q].w;
        *(float4*)(edge + (size_t)gj2[sh] * 64 + c) = rr;
      }
    }
  }
}

// -------- einsum1 via MFMA, edge fp32 read + LDS bf16 transpose --------
__global__ void __launch_bounds__(512) hyperAccumMfmaKernel(
    const float* __restrict__ edge, const __bf16* __restrict__ hyperT,
    float* __restrict__ partials) {
  __shared__ __bf16 sE[2][64][72];
  const int tid  = threadIdx.x;
  const int lane = tid & 63;
  const int wave = tid >> 6;          // 0..7
  const int l16 = lane & 15, quad = lane >> 4;
  const int e0base = blockIdx.x * (ACC_NCH * ACC_CHUNK);
  const int d  = tid & 63;
  const int eg = tid >> 6;

  float rv[8];
  auto gload = [&](int c) {
    const int ebase = e0base + c * ACC_CHUNK + eg * 8;
    const float* p = edge + (size_t)ebase * 64 + d;
    if (ebase + 8 <= E_N) {
      #pragma unroll
      for (int i = 0; i < 8; ++i) rv[i] = p[i * 64];
    } else {
      #pragma unroll
      for (int i = 0; i < 8; ++i) rv[i] = (ebase + i < E_N) ? p[i * 64] : 0.f;
    }
  };
  auto swrite = [&](int b) {
    bf16x8 pk;
    #pragma unroll
    for (int i = 0; i < 8; ++i) pk[i] = (__bf16)rv[i];
    *(bf16x8*)&sE[b][d][eg * 8] = pk;
  };

  f32x4 acc[4];
  #pragma unroll
  for (int dt = 0; dt < 4; ++dt) acc[dt] = (f32x4){0.f, 0.f, 0.f, 0.f};

  gload(0); swrite(0);
  __syncthreads();
  for (int c = 0; c < ACC_NCH; ++c) {
    const int nb = c & 1;
    if (c + 1 < ACC_NCH) gload(c + 1);
    #pragma unroll
    for (int ks = 0; ks < 2; ++ks) {
      const int eoff = c * ACC_CHUNK + ks * 32 + quad * 8;
      const bf16x8 B = *(const bf16x8*)(hyperT + (size_t)(wave * 16 + l16) * E_PAD + e0base + eoff);
      bf16x8 A[4];
      #pragma unroll
      for (int dt = 0; dt < 4; ++dt)
        A[dt] = *(const bf16x8*)&sE[nb][dt * 16 + l16][ks * 32 + quad * 8];
      #pragma unroll
      for (int dt = 0; dt < 4; ++dt)
        acc[dt] = __builtin_amdgcn_mfma_f32_16x16x32_bf16(A[dt], B, acc[dt], 0, 0, 0);
    }
    if (c + 1 < ACC_NCH) {
      __syncthreads();
      swrite(nb ^ 1);
      __syncthreads();
    }
  }
  float* pp = partials + (size_t)blockIdx.x * 8192;
  const int h = wave * 16 + l16;
  #pragma unroll
  for (int dt = 0; dt < 4; ++dt)
    #pragma unroll
    for (int reg = 0; reg < 4; ++reg) {
      const int dd = dt * 16 + quad * 4 + reg;
      pp[dd * 128 + h] = acc[dt][reg];
    }
}

// -------- single-stage reduce over NB_ACC partials + leaky -> HEtT bf16 --------
__global__ void __launch_bounds__(256) reduceKernel(const float* __restrict__ partials,
                                                    __bf16* __restrict__ HEtT) {
  __shared__ float sd[8][33];
  const int tid = threadIdx.x;
  const int o = blockIdx.x * 32 + (tid & 31);
  const int g = tid >> 5;   // 0..7
  float s = 0.f;
  #pragma unroll 4
  for (int b = g * 32; b < (g + 1) * 32; ++b) s += partials[(size_t)b * 8192 + o];
  sd[g][tid & 31] = s;
  __syncthreads();
  if (tid < 32) {
    float t = 0.f;
    #pragma unroll
    for (int k = 0; k < 8; ++k) t += sd[k][tid];
    HEtT[blockIdx.x * 32 + tid] = (__bf16)leaky(t);
  }
}

// -------- einsum2 via MFMA + residual --------
__global__ void __launch_bounds__(256) nodeUpdateMfmaKernel(
    const __bf16* __restrict__ HEtT, const __bf16* __restrict__ hyperB,
    float* __restrict__ edge) {
  const int tid  = threadIdx.x;
  const int lane = tid & 63;
  const int wave = tid >> 6;
  const int l16 = lane & 15, quad = lane >> 4;
  bf16x8 Bf[4][4];  // [kc][dt]
  #pragma unroll
  for (int kc = 0; kc < 4; ++kc)
    #pragma unroll
    for (int dt = 0; dt < 4; ++dt)
      Bf[kc][dt] = *(const bf16x8*)(HEtT + (dt * 16 + l16) * 128 + kc * 32 + quad * 8);
  const int wv = blockIdx.x * 4 + wave;
  for (int t = wv; t < E_N / 16; t += 2048) {
    const int e0 = t * 16;
    bf16x8 A[4];
    #pragma unroll
    for (int kc = 0; kc < 4; ++kc)
      A[kc] = *(const bf16x8*)(hyperB + (size_t)(e0 + l16) * 128 + kc * 32 + quad * 8);
    f32x4 acc[4];
    #pragma unroll
    for (int dt = 0; dt < 4; ++dt) acc[dt] = (f32x4){0.f, 0.f, 0.f, 0.f};
    #pragma unroll
    for (int kc = 0; kc < 4; ++kc)
      #pragma unroll
      for (int dt = 0; dt < 4; ++dt)
        acc[dt] = __builtin_amdgcn_mfma_f32_16x16x32_bf16(A[kc], Bf[kc][dt], acc[dt], 0, 0, 0);
    #pragma unroll
    for (int dt = 0; dt < 4; ++dt) {
      const int d = dt * 16 + l16;
      #pragma unroll
      for (int reg = 0; reg < 4; ++reg) {
        const int e = e0 + quad * 4 + reg;
        float* ep = edge + (size_t)e * 64 + d;
        *ep = *ep + leaky(acc[dt][reg]);
      }
    }
  }
}

// -------- bucket gather-sum: 16-lane groups, float4, list broadcast via shfl --------
__global__ void gatherSumKernel(const float* __restrict__ edge,
                                const int* __restrict__ cnt,
                                const int* __restrict__ list,
                                float* __restrict__ out) {
  const int tid = threadIdx.x;
  const int sub = tid & 15;
  const int grpInWave = (tid >> 4) & 3;
  const int gid = blockIdx.x * 16 + (tid >> 4);
  const int nG = gridDim.x * 16;
  for (int r = gid; r < NROW; r += nG) {
    const int n = min(cnt[r], BUCKET_CAP);
    int eL = (sub < n) ? list[(size_t)r * BUCKET_CAP + sub] : 0;
    float4 acc = make_float4(0.f, 0.f, 0.f, 0.f);
    for (int i = 0; i < n; ++i) {
      const int e = __shfl(eL, grpInWave * 16 + i, 64);
      const float4 v = *(const float4*)(edge + (size_t)e * 64 + sub * 4);
      acc.x += v.x; acc.y += v.y; acc.z += v.z; acc.w += v.w;
    }
    *(float4*)(out + (size_t)r * 64 + sub * 4) = acc;
  }
}

extern "C" void kernel_launch(void* const* d_in, const int* in_sizes, int n_in,
                              void* d_out, int out_size, void* d_ws, size_t ws_size,
                              hipStream_t stream) {
  const float* uE    = (const float*)d_in[0];
  const float* iE    = (const float*)d_in[1];
  const float* T     = (const float*)d_in[2];
  const float* hyper = (const float*)d_in[3];
  const int*   src   = (const int*)d_in[4];
  const int*   tgt   = (const int*)d_in[5];
  const int*   val   = (const int*)d_in[6];
  float* out = (float*)d_out;
  float* ws  = (float*)d_ws;

  float*  edge     = ws;                                 // 6,400,000 floats
  float*  partials = ws + 6400000;                       // NB_ACC*8192 (region reserved 4,194,304)
  __bf16* HEtT     = (__bf16*)(ws + 6400000 + 4194304 + 65536);  // 8192 bf16
  // perm overlay on partials (dead until GNN loop runs)
  int* perm    = (int*)partials;
  int* permSrc = perm + 8 * BIN_CAP;
  int* permTgt = permSrc + 8 * BIN_CAP;
  int* cnt8    = permTgt + 8 * BIN_CAP;
  // bucket region
  int* cnt  = (int*)(ws + 6400000 + 4194304 + 65536 + 4096);  // NROW+2 ints
  int* list = cnt + (NROW + 4);                               // NROW*BUCKET_CAP ints
  // bf16 buffers (16B-aligned offsets)
  __bf16* hyperT = (__bf16*)(ws + 15136256);             // 128 * E_PAD bf16
  __bf16* hyperB = (__bf16*)(ws + 22476288);             // E_N * 128 bf16
  __bf16* Tt     = (__bf16*)(ws + 28876288);             // 8*64*64 bf16 = 64 KB

  prepKernel<<<NB_INIT + NB_CONV, 256, 0, stream>>>(cnt, cnt8, T, Tt, hyper, hyperT, hyperB);
  binKernel<<<(E_N + 255) / 256, 256, 0, stream>>>(val, src, tgt, perm, permSrc, permTgt, cnt8, cnt, list);
  stageAMfmaKernel<<<dim3(BIN_CAP / 128, 8), 256, 0, stream>>>(uE, iE, Tt, permSrc, permTgt, perm, cnt8, edge);

  for (int layer = 0; layer < 2; ++layer) {
    hyperAccumMfmaKernel<<<NB_ACC, 512, 0, stream>>>(edge, hyperT, partials);
    reduceKernel<<<256, 256, 0, stream>>>(partials, HEtT);
    nodeUpdateMfmaKernel<<<512, 256, 0, stream>>>(HEtT, hyperB, edge);
  }

  gatherSumKernel<<<12500, 256, 0, stream>>>(edge, cnt, list, out);
}

// Round 13
// 280.566 us; speedup vs baseline: 1.0094x; 1.0094x over previous
//
#include <hip/hip_runtime.h>

#define E_N     100000
#define USER_N  100000
#define NROW    200000
#define NB_ACC  256
#define BIN_CAP 16384
#define E_PAD   114688  // 256 blocks * 7 chunks * 64 edges
#define ACC_NCH 7
#define ACC_CHUNK 64
#define BUCKET_CAP 16
#define NB_INIT 782     // 782*256 = 200192 >= NROW+2
#define NB_CONV 1792    // E_PAD/64

typedef __bf16 bf16x8 __attribute__((ext_vector_type(8)));
typedef __bf16 bf16x4 __attribute__((ext_vector_type(4)));
typedef float  f32x4  __attribute__((ext_vector_type(4)));

__device__ __forceinline__ float leaky(float x) { return x > 0.f ? x : 0.5f * x; }

// -------- prep: init counts + Tt build + hyper conversion --------
// blocks [0, NB_INIT): zero cnt/cnt8; first 8 also build Tt[v][k][d] = T[v][d][k] bf16
// blocks [NB_INIT, ..): hyper fp32 [E,128] -> hyperT bf16 [128][E_PAD] + hyperB bf16 [E][128].
// hyperT store: 4 passes, 8 lanes per h-row, bf16x8/lane -> 128B segments (was 32x16B/instr).
__global__ void __launch_bounds__(256) prepKernel(
    int* __restrict__ cnt, int* __restrict__ cnt8,
    const float* __restrict__ T, __bf16* __restrict__ Tt,
    const float* __restrict__ hyper, __bf16* __restrict__ hyperT,
    __bf16* __restrict__ hyperB) {
  __shared__ __bf16 sT[128][72];
  const int b = blockIdx.x;
  const int tid = threadIdx.x;
  if (b < NB_INIT) {
    const int i = b * 256 + tid;
    if (i < NROW + 2) cnt[i] = 0;
    if (i < 8) cnt8[i] = 0;
    if (b < 8) {
      const float* Tv = T + (size_t)b * 4096;
      __bf16* Tb = Tt + (size_t)b * 4096;
      for (int idx = tid; idx < 4096; idx += 256) {
        const int d = idx >> 6, k = idx & 63;
        Tb[k * 64 + d] = (__bf16)Tv[idx];
      }
    }
    return;
  }
  const int cb = b - NB_INIT;
  const int e0 = cb * 64;
  if (e0 >= E_N) {
    bf16x8 z;
    #pragma unroll
    for (int i = 0; i < 8; ++i) z[i] = (__bf16)0.f;
    #pragma unroll
    for (int pass = 0; pass < 4; ++pass) {
      const int hh = pass * 32 + (tid >> 3);
      const int e8 = (tid & 7) * 8;
      *(bf16x8*)(hyperT + (size_t)hh * E_PAD + e0 + e8) = z;
    }
    return;
  }
  // batch all 8 loads first (MLP=8)
  float4 v[8];
  #pragma unroll
  for (int r = 0; r < 8; ++r) {
    const int idx = r * 256 + tid;
    const int e = idx >> 5, h4 = (idx & 31) * 4;
    v[r] = make_float4(0.f, 0.f, 0.f, 0.f);
    if (e0 + e < E_N) v[r] = *(const float4*)(hyper + (size_t)(e0 + e) * 128 + h4);
  }
  // convert + store (hyperB global, sT swizzled LDS: col' = col ^ (4*((row>>2)&15)))
  #pragma unroll
  for (int r = 0; r < 8; ++r) {
    const int idx = r * 256 + tid;
    const int e = idx >> 5, h4 = (idx & 31) * 4;
    const int ce = e ^ ((idx & 15) * 4);
    bf16x4 pk;
    pk[0] = (__bf16)v[r].x; pk[1] = (__bf16)v[r].y;
    pk[2] = (__bf16)v[r].z; pk[3] = (__bf16)v[r].w;
    if (e0 + e < E_N)
      *(bf16x4*)(hyperB + (size_t)(e0 + e) * 128 + h4) = pk;
    sT[h4 + 0][ce] = pk[0]; sT[h4 + 1][ce] = pk[1];
    sT[h4 + 2][ce] = pk[2]; sT[h4 + 3][ce] = pk[3];
  }
  __syncthreads();
  // output: lane-group-of-8 per h-row -> one bf16x8 store/lane, 128B segments
  #pragma unroll
  for (int pass = 0; pass < 4; ++pass) {
    const int hh = pass * 32 + (tid >> 3);
    const int e8 = (tid & 7) * 8;
    const int swz = ((hh >> 2) & 15) * 4;
    const bf16x4 lo = *(const bf16x4*)&sT[hh][(e8 + 0) ^ swz];
    const bf16x4 hi = *(const bf16x4*)&sT[hh][(e8 + 4) ^ swz];
    bf16x8 o;
    o[0] = lo[0]; o[1] = lo[1]; o[2] = lo[2]; o[3] = lo[3];
    o[4] = hi[0]; o[5] = hi[1]; o[6] = hi[2]; o[7] = hi[3];
    *(bf16x8*)(hyperT + (size_t)hh * E_PAD + e0 + e8) = o;
  }
}

// -------- binning by etype + direct bucket fill --------
__global__ void binKernel(const int* __restrict__ val, const int* __restrict__ src,
                          const int* __restrict__ tgt,
                          int* __restrict__ perm, int* __restrict__ permSrc,
                          int* __restrict__ permTgt,
                          int* __restrict__ cnt8, int* __restrict__ cnt,
                          int* __restrict__ list) {
  __shared__ int lh[8], lbase[8];
  const int tid = threadIdx.x;
  if (tid < 8) lh[tid] = 0;
  __syncthreads();
  const int e = blockIdx.x * 256 + tid;
  int v = -1, slot = 0, s = 0, t = 0;
  if (e < E_N) {
    v = val[e]; s = src[e]; t = tgt[e];
    slot = atomicAdd(&lh[v], 1);
    const int ps = atomicAdd(&cnt[s], 1);
    if (ps < BUCKET_CAP) list[(size_t)s * BUCKET_CAP + ps] = e;
    const int pt = atomicAdd(&cnt[USER_N + t], 1);
    if (pt < BUCKET_CAP) list[(size_t)(USER_N + t) * BUCKET_CAP + pt] = e;
  }
  __syncthreads();
  if (tid < 8) lbase[tid] = atomicAdd(&cnt8[tid], lh[tid]);
  __syncthreads();
  if (v >= 0) {
    const int p = v * BIN_CAP + lbase[v] + slot;
    perm[p] = e; permSrc[p] = s; permTgt[p] = t;
  }
}

// -------- Stage A: 32 edges/wave (2 subtiles), batched gathers, 1024 blocks for TLP --------
__global__ void __launch_bounds__(256) stageAMfmaKernel(
    const float* __restrict__ uE, const float* __restrict__ iE, const __bf16* __restrict__ Tt,
    const int* __restrict__ permSrc, const int* __restrict__ permTgt,
    const int* __restrict__ perm, const int* __restrict__ cnt8,
    float* __restrict__ edge) {
  __shared__ float sC[4][16][68];
  const int v  = blockIdx.y;
  const int nE = min(cnt8[v], BIN_CAP);
  const int tid  = threadIdx.x;
  const int lane = tid & 63;
  const int wave = tid >> 6;
  const int l16 = lane & 15, quad = lane >> 4;
  const int wbase = blockIdx.x * 128 + wave * 32;   // this wave's 32 edges
  if (wbase >= nE) return;

  bf16x8 Bf[2][4];
  #pragma unroll
  for (int kc = 0; kc < 2; ++kc)
    #pragma unroll
    for (int nt = 0; nt < 4; ++nt)
      Bf[kc][nt] = *(const bf16x8*)(Tt + (size_t)v * 4096 + (nt * 16 + l16) * 64 + kc * 32 + quad * 8);

  int sI[2], tI[2], eI[2];
  #pragma unroll
  for (int s = 0; s < 2; ++s) {
    const int eoffS = wbase + s * 16;
    const bool lv = (eoffS + l16 < nE);
    const int p = v * BIN_CAP + (lv ? eoffS + l16 : 0);
    sI[s] = permSrc[p]; tI[s] = permTgt[p]; eI[s] = perm[p];
  }

  float4 f0[2][2], f1[2][2];
  #pragma unroll
  for (int s = 0; s < 2; ++s)
    #pragma unroll
    for (int kc = 0; kc < 2; ++kc) {
      const float* ap = uE + (size_t)sI[s] * 64 + kc * 32 + quad * 8;
      f0[s][kc] = *(const float4*)ap;
      f1[s][kc] = *(const float4*)(ap + 4);
    }

  const int r  = lane >> 2;
  const int c0 = (lane & 3) * 4;

  // iE prefetch for both subtiles
  float4 iv[2][4];
  int tj2[2], gj2[2];
  #pragma unroll
  for (int sh = 0; sh < 2; ++sh) {
    tj2[sh] = __shfl(tI[sh], r, 64);
    gj2[sh] = __shfl(eI[sh], r, 64);
    #pragma unroll
    for (int q = 0; q < 4; ++q)
      iv[sh][q] = *(const float4*)(iE + (size_t)tj2[sh] * 64 + c0 + q * 16);
  }

  f32x4 acc[2][4];
  #pragma unroll
  for (int sh = 0; sh < 2; ++sh)
    #pragma unroll
    for (int nt = 0; nt < 4; ++nt) acc[sh][nt] = (f32x4){0.f, 0.f, 0.f, 0.f};
  #pragma unroll
  for (int sh = 0; sh < 2; ++sh) {
    #pragma unroll
    for (int kc = 0; kc < 2; ++kc) {
      bf16x8 a;
      a[0] = (__bf16)f0[sh][kc].x; a[1] = (__bf16)f0[sh][kc].y;
      a[2] = (__bf16)f0[sh][kc].z; a[3] = (__bf16)f0[sh][kc].w;
      a[4] = (__bf16)f1[sh][kc].x; a[5] = (__bf16)f1[sh][kc].y;
      a[6] = (__bf16)f1[sh][kc].z; a[7] = (__bf16)f1[sh][kc].w;
      #pragma unroll
      for (int nt = 0; nt < 4; ++nt)
        acc[sh][nt] = __builtin_amdgcn_mfma_f32_16x16x32_bf16(a, Bf[kc][nt], acc[sh][nt], 0, 0, 0);
    }
  }
  #pragma unroll
  for (int sh = 0; sh < 2; ++sh) {
    const int eoffS = wbase + sh * 16;
    #pragma unroll
    for (int nt = 0; nt < 4; ++nt)
      #pragma unroll
      for (int reg = 0; reg < 4; ++reg)
        sC[wave][quad * 4 + reg][nt * 16 + l16] = acc[sh][nt][reg];
    if (eoffS + r < nE) {
      #pragma unroll
      for (int q = 0; q < 4; ++q) {
        const int c = c0 + q * 16;
        const float4 cv = *(const float4*)&sC[wave][r][c];
        float4 rr;
        rr.x = cv.x * iv[sh][q].x; rr.y = cv.y * iv[sh][q].y;
        rr.z = cv.z * iv[sh][q].z; rr.w = cv.w * iv[sh][q].w;
        *(float4*)(edge + (size_t)gj2[sh] * 64 + c) = rr;
      }
    }
  }
}

// -------- einsum1 via MFMA, edge fp32 read + LDS bf16 transpose --------
__global__ void __launch_bounds__(512) hyperAccumMfmaKernel(
    const float* __restrict__ edge, const __bf16* __restrict__ hyperT,
    float* __restrict__ partials) {
  __shared__ __bf16 sE[2][64][72];
  const int tid  = threadIdx.x;
  const int lane = tid & 63;
  const int wave = tid >> 6;          // 0..7
  const int l16 = lane & 15, quad = lane >> 4;
  const int e0base = blockIdx.x * (ACC_NCH * ACC_CHUNK);
  const int d  = tid & 63;
  const int eg = tid >> 6;

  float rv[8];
  auto gload = [&](int c) {
    const int ebase = e0base + c * ACC_CHUNK + eg * 8;
    const float* p = edge + (size_t)ebase * 64 + d;
    if (ebase + 8 <= E_N) {
      #pragma unroll
      for (int i = 0; i < 8; ++i) rv[i] = p[i * 64];
    } else {
      #pragma unroll
      for (int i = 0; i < 8; ++i) rv[i] = (ebase + i < E_N) ? p[i * 64] : 0.f;
    }
  };
  auto swrite = [&](int b) {
    bf16x8 pk;
    #pragma unroll
    for (int i = 0; i < 8; ++i) pk[i] = (__bf16)rv[i];
    *(bf16x8*)&sE[b][d][eg * 8] = pk;
  };

  f32x4 acc[4];
  #pragma unroll
  for (int dt = 0; dt < 4; ++dt) acc[dt] = (f32x4){0.f, 0.f, 0.f, 0.f};

  gload(0); swrite(0);
  __syncthreads();
  for (int c = 0; c < ACC_NCH; ++c) {
    const int nb = c & 1;
    if (c + 1 < ACC_NCH) gload(c + 1);
    #pragma unroll
    for (int ks = 0; ks < 2; ++ks) {
      const int eoff = c * ACC_CHUNK + ks * 32 + quad * 8;
      const bf16x8 B = *(const bf16x8*)(hyperT + (size_t)(wave * 16 + l16) * E_PAD + e0base + eoff);
      bf16x8 A[4];
      #pragma unroll
      for (int dt = 0; dt < 4; ++dt)
        A[dt] = *(const bf16x8*)&sE[nb][dt * 16 + l16][ks * 32 + quad * 8];
      #pragma unroll
      for (int dt = 0; dt < 4; ++dt)
        acc[dt] = __builtin_amdgcn_mfma_f32_16x16x32_bf16(A[dt], B, acc[dt], 0, 0, 0);
    }
    if (c + 1 < ACC_NCH) {
      __syncthreads();
      swrite(nb ^ 1);
      __syncthreads();
    }
  }
  float* pp = partials + (size_t)blockIdx.x * 8192;
  const int h = wave * 16 + l16;
  #pragma unroll
  for (int dt = 0; dt < 4; ++dt)
    #pragma unroll
    for (int reg = 0; reg < 4; ++reg) {
      const int dd = dt * 16 + quad * 4 + reg;
      pp[dd * 128 + h] = acc[dt][reg];
    }
}

// -------- single-stage reduce over NB_ACC partials + leaky -> HEtT bf16 --------
__global__ void __launch_bounds__(256) reduceKernel(const float* __restrict__ partials,
                                                    __bf16* __restrict__ HEtT) {
  __shared__ float sd[8][33];
  const int tid = threadIdx.x;
  const int o = blockIdx.x * 32 + (tid & 31);
  const int g = tid >> 5;   // 0..7
  float s = 0.f;
  #pragma unroll 4
  for (int b = g * 32; b < (g + 1) * 32; ++b) s += partials[(size_t)b * 8192 + o];
  sd[g][tid & 31] = s;
  __syncthreads();
  if (tid < 32) {
    float t = 0.f;
    #pragma unroll
    for (int k = 0; k < 8; ++k) t += sd[k][tid];
    HEtT[blockIdx.x * 32 + tid] = (__bf16)leaky(t);
  }
}

// -------- einsum2 via MFMA + residual --------
__global__ void __launch_bounds__(256) nodeUpdateMfmaKernel(
    const __bf16* __restrict__ HEtT, const __bf16* __restrict__ hyperB,
    float* __restrict__ edge) {
  const int tid  = threadIdx.x;
  const int lane = tid & 63;
  const int wave = tid >> 6;
  const int l16 = lane & 15, quad = lane >> 4;
  bf16x8 Bf[4][4];  // [kc][dt]
  #pragma unroll
  for (int kc = 0; kc < 4; ++kc)
    #pragma unroll
    for (int dt = 0; dt < 4; ++dt)
      Bf[kc][dt] = *(const bf16x8*)(HEtT + (dt * 16 + l16) * 128 + kc * 32 + quad * 8);
  const int wv = blockIdx.x * 4 + wave;
  for (int t = wv; t < E_N / 16; t += 2048) {
    const int e0 = t * 16;
    bf16x8 A[4];
    #pragma unroll
    for (int kc = 0; kc < 4; ++kc)
      A[kc] = *(const bf16x8*)(hyperB + (size_t)(e0 + l16) * 128 + kc * 32 + quad * 8);
    f32x4 acc[4];
    #pragma unroll
    for (int dt = 0; dt < 4; ++dt) acc[dt] = (f32x4){0.f, 0.f, 0.f, 0.f};
    #pragma unroll
    for (int kc = 0; kc < 4; ++kc)
      #pragma unroll
      for (int dt = 0; dt < 4; ++dt)
        acc[dt] = __builtin_amdgcn_mfma_f32_16x16x32_bf16(A[kc], Bf[kc][dt], acc[dt], 0, 0, 0);
    #pragma unroll
    for (int dt = 0; dt < 4; ++dt) {
      const int d = dt * 16 + l16;
      #pragma unroll
      for (int reg = 0; reg < 4; ++reg) {
        const int e = e0 + quad * 4 + reg;
        float* ep = edge + (size_t)e * 64 + d;
        *ep = *ep + leaky(acc[dt][reg]);
      }
    }
  }
}

// -------- bucket gather-sum: 16-lane groups, float4, list broadcast via shfl --------
__global__ void gatherSumKernel(const float* __restrict__ edge,
                                const int* __restrict__ cnt,
                                const int* __restrict__ list,
                                float* __restrict__ out) {
  const int tid = threadIdx.x;
  const int sub = tid & 15;
  const int grpInWave = (tid >> 4) & 3;
  const int gid = blockIdx.x * 16 + (tid >> 4);
  const int nG = gridDim.x * 16;
  for (int r = gid; r < NROW; r += nG) {
    const int n = min(cnt[r], BUCKET_CAP);
    int eL = (sub < n) ? list[(size_t)r * BUCKET_CAP + sub] : 0;
    float4 acc = make_float4(0.f, 0.f, 0.f, 0.f);
    for (int i = 0; i < n; ++i) {
      const int e = __shfl(eL, grpInWave * 16 + i, 64);
      const float4 v = *(const float4*)(edge + (size_t)e * 64 + sub * 4);
      acc.x += v.x; acc.y += v.y; acc.z += v.z; acc.w += v.w;
    }
    *(float4*)(out + (size_t)r * 64 + sub * 4) = acc;
  }
}

extern "C" void kernel_launch(void* const* d_in, const int* in_sizes, int n_in,
                              void* d_out, int out_size, void* d_ws, size_t ws_size,
                              hipStream_t stream) {
  const float* uE    = (const float*)d_in[0];
  const float* iE    = (const float*)d_in[1];
  const float* T     = (const float*)d_in[2];
  const float* hyper = (const float*)d_in[3];
  const int*   src   = (const int*)d_in[4];
  const int*   tgt   = (const int*)d_in[5];
  const int*   val   = (const int*)d_in[6];
  float* out = (float*)d_out;
  float* ws  = (float*)d_ws;

  float*  edge     = ws;                                 // 6,400,000 floats
  float*  partials = ws + 6400000;                       // NB_ACC*8192 (region reserved 4,194,304)
  __bf16* HEtT     = (__bf16*)(ws + 6400000 + 4194304 + 65536);  // 8192 bf16
  // perm overlay on partials (dead until GNN loop runs)
  int* perm    = (int*)partials;
  int* permSrc = perm + 8 * BIN_CAP;
  int* permTgt = permSrc + 8 * BIN_CAP;
  int* cnt8    = permTgt + 8 * BIN_CAP;
  // bucket region
  int* cnt  = (int*)(ws + 6400000 + 4194304 + 65536 + 4096);  // NROW+2 ints
  int* list = cnt + (NROW + 4);                               // NROW*BUCKET_CAP ints
  // bf16 buffers (16B-aligned offsets)
  __bf16* hyperT = (__bf16*)(ws + 15136256);             // 128 * E_PAD bf16
  __bf16* hyperB = (__bf16*)(ws + 22476288);             // E_N * 128 bf16
  __bf16* Tt     = (__bf16*)(ws + 28876288);             // 8*64*64 bf16 = 64 KB

  prepKernel<<<NB_INIT + NB_CONV, 256, 0, stream>>>(cnt, cnt8, T, Tt, hyper, hyperT, hyperB);
  binKernel<<<(E_N + 255) / 256, 256, 0, stream>>>(val, src, tgt, perm, permSrc, permTgt, cnt8, cnt, list);
  stageAMfmaKernel<<<dim3(BIN_CAP / 128, 8), 256, 0, stream>>>(uE, iE, Tt, permSrc, permTgt, perm, cnt8, edge);

  for (int layer = 0; layer < 2; ++layer) {
    hyperAccumMfmaKernel<<<NB_ACC, 512, 0, stream>>>(edge, hyperT, partials);
    reduceKernel<<<256, 256, 0, stream>>>(partials, HEtT);
    nodeUpdateMfmaKernel<<<512, 256, 0, stream>>>(HEtT, hyperB, edge);
  }

  gatherSumKernel<<<12500, 256, 0, stream>>>(edge, cnt, list, out);
}

// Round 14
// 275.297 us; speedup vs baseline: 1.0287x; 1.0191x over previous
//
#include <hip/hip_runtime.h>

#define E_N     100000
#define USER_N  100000
#define NROW    200000
#define NB_ACC  256
#define BIN_CAP 16384
#define ACC_NCH 7
#define ACC_CHUNK 64
#define BUCKET_CAP 16
#define NB_INIT 782     // 782*256 = 200192 >= NROW+2
#define NB_CONV 1792

typedef __bf16 bf16x8 __attribute__((ext_vector_type(8)));
typedef __bf16 bf16x4 __attribute__((ext_vector_type(4)));
typedef float  f32x4  __attribute__((ext_vector_type(4)));

__device__ __forceinline__ float leaky(float x) { return x > 0.f ? x : 0.5f * x; }

// -------- prep: init counts + Tt build + streaming hyper fp32 -> hyperB bf16 --------
// blocks [0, NB_INIT): zero cnt/cnt8; first 8 also build Tt[v][k][d] = T[v][d][k] bf16
// blocks [NB_INIT, ..): grid-stride float4 convert (no LDS, no transpose — consumer transposes).
__global__ void __launch_bounds__(256) prepKernel(
    int* __restrict__ cnt, int* __restrict__ cnt8,
    const float* __restrict__ T, __bf16* __restrict__ Tt,
    const float* __restrict__ hyper, __bf16* __restrict__ hyperB) {
  const int b = blockIdx.x;
  const int tid = threadIdx.x;
  if (b < NB_INIT) {
    const int i = b * 256 + tid;
    if (i < NROW + 2) cnt[i] = 0;
    if (i < 8) cnt8[i] = 0;
    if (b < 8) {
      const float* Tv = T + (size_t)b * 4096;
      __bf16* Tb = Tt + (size_t)b * 4096;
      for (int idx = tid; idx < 4096; idx += 256) {
        const int d = idx >> 6, k = idx & 63;
        Tb[k * 64 + d] = (__bf16)Tv[idx];
      }
    }
    return;
  }
  const int gtid = (b - NB_INIT) * 256 + tid;
  const int stride = NB_CONV * 256;
  const float4* h4 = (const float4*)hyper;
  for (int i = gtid; i < E_N * 32; i += stride) {
    const float4 v = h4[i];
    bf16x4 pk;
    pk[0] = (__bf16)v.x; pk[1] = (__bf16)v.y;
    pk[2] = (__bf16)v.z; pk[3] = (__bf16)v.w;
    *(bf16x4*)(hyperB + (size_t)i * 4) = pk;
  }
}

// -------- binning by etype + direct bucket fill --------
__global__ void binKernel(const int* __restrict__ val, const int* __restrict__ src,
                          const int* __restrict__ tgt,
                          int* __restrict__ perm, int* __restrict__ permSrc,
                          int* __restrict__ permTgt,
                          int* __restrict__ cnt8, int* __restrict__ cnt,
                          int* __restrict__ list) {
  __shared__ int lh[8], lbase[8];
  const int tid = threadIdx.x;
  if (tid < 8) lh[tid] = 0;
  __syncthreads();
  const int e = blockIdx.x * 256 + tid;
  int v = -1, slot = 0, s = 0, t = 0;
  if (e < E_N) {
    v = val[e]; s = src[e]; t = tgt[e];
    slot = atomicAdd(&lh[v], 1);
    const int ps = atomicAdd(&cnt[s], 1);
    if (ps < BUCKET_CAP) list[(size_t)s * BUCKET_CAP + ps] = e;
    const int pt = atomicAdd(&cnt[USER_N + t], 1);
    if (pt < BUCKET_CAP) list[(size_t)(USER_N + t) * BUCKET_CAP + pt] = e;
  }
  __syncthreads();
  if (tid < 8) lbase[tid] = atomicAdd(&cnt8[tid], lh[tid]);
  __syncthreads();
  if (v >= 0) {
    const int p = v * BIN_CAP + lbase[v] + slot;
    perm[p] = e; permSrc[p] = s; permTgt[p] = t;
  }
}

// -------- Stage A: 32 edges/wave (2 subtiles), batched gathers, 1024 blocks for TLP --------
__global__ void __launch_bounds__(256) stageAMfmaKernel(
    const float* __restrict__ uE, const float* __restrict__ iE, const __bf16* __restrict__ Tt,
    const int* __restrict__ permSrc, const int* __restrict__ permTgt,
    const int* __restrict__ perm, const int* __restrict__ cnt8,
    float* __restrict__ edge) {
  __shared__ float sC[4][16][68];
  const int v  = blockIdx.y;
  const int nE = min(cnt8[v], BIN_CAP);
  const int tid  = threadIdx.x;
  const int lane = tid & 63;
  const int wave = tid >> 6;
  const int l16 = lane & 15, quad = lane >> 4;
  const int wbase = blockIdx.x * 128 + wave * 32;
  if (wbase >= nE) return;

  bf16x8 Bf[2][4];
  #pragma unroll
  for (int kc = 0; kc < 2; ++kc)
    #pragma unroll
    for (int nt = 0; nt < 4; ++nt)
      Bf[kc][nt] = *(const bf16x8*)(Tt + (size_t)v * 4096 + (nt * 16 + l16) * 64 + kc * 32 + quad * 8);

  int sI[2], tI[2], eI[2];
  #pragma unroll
  for (int s = 0; s < 2; ++s) {
    const int eoffS = wbase + s * 16;
    const bool lv = (eoffS + l16 < nE);
    const int p = v * BIN_CAP + (lv ? eoffS + l16 : 0);
    sI[s] = permSrc[p]; tI[s] = permTgt[p]; eI[s] = perm[p];
  }

  float4 f0[2][2], f1[2][2];
  #pragma unroll
  for (int s = 0; s < 2; ++s)
    #pragma unroll
    for (int kc = 0; kc < 2; ++kc) {
      const float* ap = uE + (size_t)sI[s] * 64 + kc * 32 + quad * 8;
      f0[s][kc] = *(const float4*)ap;
      f1[s][kc] = *(const float4*)(ap + 4);
    }

  const int r  = lane >> 2;
  const int c0 = (lane & 3) * 4;

  float4 iv[2][4];
  int tj2[2], gj2[2];
  #pragma unroll
  for (int sh = 0; sh < 2; ++sh) {
    tj2[sh] = __shfl(tI[sh], r, 64);
    gj2[sh] = __shfl(eI[sh], r, 64);
    #pragma unroll
    for (int q = 0; q < 4; ++q)
      iv[sh][q] = *(const float4*)(iE + (size_t)tj2[sh] * 64 + c0 + q * 16);
  }

  f32x4 acc[2][4];
  #pragma unroll
  for (int sh = 0; sh < 2; ++sh)
    #pragma unroll
    for (int nt = 0; nt < 4; ++nt) acc[sh][nt] = (f32x4){0.f, 0.f, 0.f, 0.f};
  #pragma unroll
  for (int sh = 0; sh < 2; ++sh) {
    #pragma unroll
    for (int kc = 0; kc < 2; ++kc) {
      bf16x8 a;
      a[0] = (__bf16)f0[sh][kc].x; a[1] = (__bf16)f0[sh][kc].y;
      a[2] = (__bf16)f0[sh][kc].z; a[3] = (__bf16)f0[sh][kc].w;
      a[4] = (__bf16)f1[sh][kc].x; a[5] = (__bf16)f1[sh][kc].y;
      a[6] = (__bf16)f1[sh][kc].z; a[7] = (__bf16)f1[sh][kc].w;
      #pragma unroll
      for (int nt = 0; nt < 4; ++nt)
        acc[sh][nt] = __builtin_amdgcn_mfma_f32_16x16x32_bf16(a, Bf[kc][nt], acc[sh][nt], 0, 0, 0);
    }
  }
  #pragma unroll
  for (int sh = 0; sh < 2; ++sh) {
    const int eoffS = wbase + sh * 16;
    #pragma unroll
    for (int nt = 0; nt < 4; ++nt)
      #pragma unroll
      for (int reg = 0; reg < 4; ++reg)
        sC[wave][quad * 4 + reg][nt * 16 + l16] = acc[sh][nt][reg];
    if (eoffS + r < nE) {
      #pragma unroll
      for (int q = 0; q < 4; ++q) {
        const int c = c0 + q * 16;
        const float4 cv = *(const float4*)&sC[wave][r][c];
        float4 rr;
        rr.x = cv.x * iv[sh][q].x; rr.y = cv.y * iv[sh][q].y;
        rr.z = cv.z * iv[sh][q].z; rr.w = cv.w * iv[sh][q].w;
        *(float4*)(edge + (size_t)gj2[sh] * 64 + c) = rr;
      }
    }
  }
}

// -------- einsum1 via MFMA: edge fp32 + hyperB bf16 both staged via LDS transpose --------
// sE double-buffered (edge), sH single-buffered (hyper, swizzled e^8*((h>>3)&7)),
// sH writes sit inside the existing two syncs. No hyperT intermediate.
__global__ void __launch_bounds__(512) hyperAccumMfmaKernel(
    const float* __restrict__ edge, const __bf16* __restrict__ hyperB,
    float* __restrict__ partials) {
  __shared__ __bf16 sE[2][64][72];
  __shared__ __bf16 sH[128][72];
  const int tid  = threadIdx.x;
  const int lane = tid & 63;
  const int wave = tid >> 6;          // 0..7
  const int l16 = lane & 15, quad = lane >> 4;
  const int e0base = blockIdx.x * (ACC_NCH * ACC_CHUNK);
  const int d  = tid & 63;
  const int eg = tid >> 6;
  // hyper staging: thread covers e_loc = (tid>>4) + pass*32, h-octet h8 = (tid&15)*8
  const int eh = tid >> 4;            // 0..31
  const int h8 = (tid & 15) * 8;
  const int hswz = 8 * ((tid & 15) & 7);

  float rv[8];
  auto gload = [&](int c) {
    const int ebase = e0base + c * ACC_CHUNK + eg * 8;
    const float* p = edge + (size_t)ebase * 64 + d;
    if (ebase + 8 <= E_N) {
      #pragma unroll
      for (int i = 0; i < 8; ++i) rv[i] = p[i * 64];
    } else {
      #pragma unroll
      for (int i = 0; i < 8; ++i) rv[i] = (ebase + i < E_N) ? p[i * 64] : 0.f;
    }
  };
  auto swrite = [&](int b) {
    bf16x8 pk;
    #pragma unroll
    for (int i = 0; i < 8; ++i) pk[i] = (__bf16)rv[i];
    *(bf16x8*)&sE[b][d][eg * 8] = pk;
  };

  bf16x8 hv[2];
  auto hload = [&](int c) {
    #pragma unroll
    for (int p = 0; p < 2; ++p) {
      const int e = e0base + c * ACC_CHUNK + p * 32 + eh;
      if (e < E_N) {
        hv[p] = *(const bf16x8*)(hyperB + (size_t)e * 128 + h8);
      } else {
        bf16x8 z;
        #pragma unroll
        for (int i = 0; i < 8; ++i) z[i] = (__bf16)0.f;
        hv[p] = z;
      }
    }
  };
  auto hwrite = [&]() {
    #pragma unroll
    for (int p = 0; p < 2; ++p) {
      const int ee = (p * 32 + eh) ^ hswz;
      #pragma unroll
      for (int j = 0; j < 8; ++j) sH[h8 + j][ee] = hv[p][j];
    }
  };

  f32x4 acc[4];
  #pragma unroll
  for (int dt = 0; dt < 4; ++dt) acc[dt] = (f32x4){0.f, 0.f, 0.f, 0.f};

  const int hh = wave * 16 + l16;
  const int bswz = 8 * ((hh >> 3) & 7);

  gload(0); hload(0);
  swrite(0); hwrite();
  __syncthreads();
  for (int c = 0; c < ACC_NCH; ++c) {
    const int nb = c & 1;
    if (c + 1 < ACC_NCH) { gload(c + 1); hload(c + 1); }
    #pragma unroll
    for (int ks = 0; ks < 2; ++ks) {
      const bf16x8 B = *(const bf16x8*)&sH[hh][(ks * 32 + quad * 8) ^ bswz];
      bf16x8 A[4];
      #pragma unroll
      for (int dt = 0; dt < 4; ++dt)
        A[dt] = *(const bf16x8*)&sE[nb][dt * 16 + l16][ks * 32 + quad * 8];
      #pragma unroll
      for (int dt = 0; dt < 4; ++dt)
        acc[dt] = __builtin_amdgcn_mfma_f32_16x16x32_bf16(A[dt], B, acc[dt], 0, 0, 0);
    }
    if (c + 1 < ACC_NCH) {
      __syncthreads();
      swrite(nb ^ 1); hwrite();
      __syncthreads();
    }
  }
  float* pp = partials + (size_t)blockIdx.x * 8192;
  const int h = wave * 16 + l16;
  #pragma unroll
  for (int dt = 0; dt < 4; ++dt)
    #pragma unroll
    for (int reg = 0; reg < 4; ++reg) {
      const int dd = dt * 16 + quad * 4 + reg;
      pp[dd * 128 + h] = acc[dt][reg];
    }
}

// -------- single-stage reduce over NB_ACC partials + leaky -> HEtT bf16 --------
__global__ void __launch_bounds__(256) reduceKernel(const float* __restrict__ partials,
                                                    __bf16* __restrict__ HEtT) {
  __shared__ float sd[8][33];
  const int tid = threadIdx.x;
  const int o = blockIdx.x * 32 + (tid & 31);
  const int g = tid >> 5;   // 0..7
  float s = 0.f;
  #pragma unroll 4
  for (int b = g * 32; b < (g + 1) * 32; ++b) s += partials[(size_t)b * 8192 + o];
  sd[g][tid & 31] = s;
  __syncthreads();
  if (tid < 32) {
    float t = 0.f;
    #pragma unroll
    for (int k = 0; k < 8; ++k) t += sd[k][tid];
    HEtT[blockIdx.x * 32 + tid] = (__bf16)leaky(t);
  }
}

// -------- einsum2 via MFMA + residual --------
__global__ void __launch_bounds__(256) nodeUpdateMfmaKernel(
    const __bf16* __restrict__ HEtT, const __bf16* __restrict__ hyperB,
    float* __restrict__ edge) {
  const int tid  = threadIdx.x;
  const int lane = tid & 63;
  const int wave = tid >> 6;
  const int l16 = lane & 15, quad = lane >> 4;
  bf16x8 Bf[4][4];  // [kc][dt]
  #pragma unroll
  for (int kc = 0; kc < 4; ++kc)
    #pragma unroll
    for (int dt = 0; dt < 4; ++dt)
      Bf[kc][dt] = *(const bf16x8*)(HEtT + (dt * 16 + l16) * 128 + kc * 32 + quad * 8);
  const int wv = blockIdx.x * 4 + wave;
  for (int t = wv; t < E_N / 16; t += 2048) {
    const int e0 = t * 16;
    bf16x8 A[4];
    #pragma unroll
    for (int kc = 0; kc < 4; ++kc)
      A[kc] = *(const bf16x8*)(hyperB + (size_t)(e0 + l16) * 128 + kc * 32 + quad * 8);
    f32x4 acc[4];
    #pragma unroll
    for (int dt = 0; dt < 4; ++dt) acc[dt] = (f32x4){0.f, 0.f, 0.f, 0.f};
    #pragma unroll
    for (int kc = 0; kc < 4; ++kc)
      #pragma unroll
      for (int dt = 0; dt < 4; ++dt)
        acc[dt] = __builtin_amdgcn_mfma_f32_16x16x32_bf16(A[kc], Bf[kc][dt], acc[dt], 0, 0, 0);
    #pragma unroll
    for (int dt = 0; dt < 4; ++dt) {
      const int d = dt * 16 + l16;
      #pragma unroll
      for (int reg = 0; reg < 4; ++reg) {
        const int e = e0 + quad * 4 + reg;
        float* ep = edge + (size_t)e * 64 + d;
        *ep = *ep + leaky(acc[dt][reg]);
      }
    }
  }
}

// -------- bucket gather-sum: 16-lane groups, float4, list broadcast via shfl --------
__global__ void gatherSumKernel(const float* __restrict__ edge,
                                const int* __restrict__ cnt,
                                const int* __restrict__ list,
                                float* __restrict__ out) {
  const int tid = threadIdx.x;
  const int sub = tid & 15;
  const int grpInWave = (tid >> 4) & 3;
  const int gid = blockIdx.x * 16 + (tid >> 4);
  const int nG = gridDim.x * 16;
  for (int r = gid; r < NROW; r += nG) {
    const int n = min(cnt[r], BUCKET_CAP);
    int eL = (sub < n) ? list[(size_t)r * BUCKET_CAP + sub] : 0;
    float4 acc = make_float4(0.f, 0.f, 0.f, 0.f);
    for (int i = 0; i < n; ++i) {
      const int e = __shfl(eL, grpInWave * 16 + i, 64);
      const float4 v = *(const float4*)(edge + (size_t)e * 64 + sub * 4);
      acc.x += v.x; acc.y += v.y; acc.z += v.z; acc.w += v.w;
    }
    *(float4*)(out + (size_t)r * 64 + sub * 4) = acc;
  }
}

extern "C" void kernel_launch(void* const* d_in, const int* in_sizes, int n_in,
                              void* d_out, int out_size, void* d_ws, size_t ws_size,
                              hipStream_t stream) {
  const float* uE    = (const float*)d_in[0];
  const float* iE    = (const float*)d_in[1];
  const float* T     = (const float*)d_in[2];
  const float* hyper = (const float*)d_in[3];
  const int*   src   = (const int*)d_in[4];
  const int*   tgt   = (const int*)d_in[5];
  const int*   val   = (const int*)d_in[6];
  float* out = (float*)d_out;
  float* ws  = (float*)d_ws;

  float*  edge     = ws;                                 // 6,400,000 floats
  float*  partials = ws + 6400000;                       // NB_ACC*8192 (region reserved 4,194,304)
  __bf16* HEtT     = (__bf16*)(ws + 6400000 + 4194304 + 65536);  // 8192 bf16
  // perm overlay on partials (dead until GNN loop runs)
  int* perm    = (int*)partials;
  int* permSrc = perm + 8 * BIN_CAP;
  int* permTgt = permSrc + 8 * BIN_CAP;
  int* cnt8    = permTgt + 8 * BIN_CAP;
  // bucket region
  int* cnt  = (int*)(ws + 6400000 + 4194304 + 65536 + 4096);  // NROW+2 ints
  int* list = cnt + (NROW + 4);                               // NROW*BUCKET_CAP ints
  // bf16 buffers (16B-aligned offsets)
  __bf16* hyperB = (__bf16*)(ws + 22476288);             // E_N * 128 bf16
  __bf16* Tt     = (__bf16*)(ws + 28876288);             // 8*64*64 bf16 = 64 KB

  prepKernel<<<NB_INIT + NB_CONV, 256, 0, stream>>>(cnt, cnt8, T, Tt, hyper, hyperB);
  binKernel<<<(E_N + 255) / 256, 256, 0, stream>>>(val, src, tgt, perm, permSrc, permTgt, cnt8, cnt, list);
  stageAMfmaKernel<<<dim3(BIN_CAP / 128, 8), 256, 0, stream>>>(uE, iE, Tt, permSrc, permTgt, perm, cnt8, edge);

  for (int layer = 0; layer < 2; ++layer) {
    hyperAccumMfmaKernel<<<NB_ACC, 512, 0, stream>>>(edge, hyperB, partials);
    reduceKernel<<<256, 256, 0, stream>>>(partials, HEtT);
    nodeUpdateMfmaKernel<<<512, 256, 0, stream>>>(HEtT, hyperB, edge);
  }

  gatherSumKernel<<<12500, 256, 0, stream>>>(edge, cnt, list, out);
}